// Round 5
// baseline (4119.196 us; speedup 1.0000x reference)
//
#include <hip/hip_runtime.h>
#include <cstdint>
#include <cstddef>

// ---------------------------------------------------------------------------
// PointNet++ (PointNetEnc) forward on MI355X.
//
// Exactness-critical parts (FPS argmax, radius test, top-K set) use
// contraction-free f32 matching numpy elementwise semantics; all cross-lane
// argmax/argmin use packed u64 keys (f32 bits are monotone for d>=0) with
// exact first-index tie-break. MLP math uses fmaf freely (5e-2 abs
// tolerance). eps reproduces jax.random.normal(key(42), (8,32)) via
// threefry2x32 (partitionable layout) + XLA erfinv.
// ---------------------------------------------------------------------------

constexpr int BATCH = 8;
constexpr int NPT0  = 4096;
constexpr int M1    = 2048;
constexpr int M2    = 512;
constexpr int KNB   = 64;
constexpr int CAP   = 1024;   // max in-radius candidates kept (mean ~137/~550)

// workspace layout (float offsets, all 16B aligned). H2G aliases X1 (X1 is
// dead after SA2); FP aliases X2 (dead after sa3_l12). Peak = 6.8 MB.
constexpr size_t O_WT1S1 = 0;        // [32][3]
constexpr size_t O_WT2S1 = 96;       // [32][32]
constexpr size_t O_WT3S1 = 1120;     // [64][32]
constexpr size_t O_WT1S2 = 3168;     // [64][67]
constexpr size_t O_WT2S2 = 7456;     // [64][64]
constexpr size_t O_WT3S2 = 11552;    // [128][64]
constexpr size_t O_WT1S3 = 19744;    // [128][131]
constexpr size_t O_WT2S3 = 36512;    // [256][128]
constexpr size_t O_POS1  = 69280;    // [8][2048][3]
constexpr size_t O_X1    = 118432;   // [8][2048][64]
constexpr size_t O_POS2  = 1167008;  // [8][512][3]
constexpr size_t O_X2    = 1179296;  // [8][512][128]  (end 1703584 = 6.8MB)
constexpr size_t O_H2G   = O_X1;     // [8][512][256] aliases X1
constexpr size_t O_FP    = O_X2;     // [8][32][512] partial maxes, aliases X2

// ---------------------------------------------------------------------------
// DPP wave-reduction helpers (CDNA row_shr ladder + row broadcasts).
// Full 64-lane reduce lands in lane 63; readlane(63) broadcasts as scalar.
// update_dpp(old=x, src=x, ...) makes invalid-source lanes keep x — identity
// for min/max, so reductions are exact.
// ---------------------------------------------------------------------------
template <int C>
__device__ __forceinline__ int dppmov(int x) {
  return __builtin_amdgcn_update_dpp(x, x, C, 0xF, 0xF, false);
}

__device__ __forceinline__ float wave_fmax_scal(float x) {
  x = fmaxf(x, __int_as_float(dppmov<0x111>(__float_as_int(x))));  // row_shr:1
  x = fmaxf(x, __int_as_float(dppmov<0x112>(__float_as_int(x))));  // row_shr:2
  x = fmaxf(x, __int_as_float(dppmov<0x114>(__float_as_int(x))));  // row_shr:4
  x = fmaxf(x, __int_as_float(dppmov<0x118>(__float_as_int(x))));  // row_shr:8
  x = fmaxf(x, __int_as_float(dppmov<0x142>(__float_as_int(x))));  // row_bcast15
  x = fmaxf(x, __int_as_float(dppmov<0x143>(__float_as_int(x))));  // row_bcast31
  return __int_as_float(__builtin_amdgcn_readlane(__float_as_int(x), 63));
}

// fused u64-key reductions: key = (hi:32 | lo:32), lexicographic.
template <int C>
__device__ __forceinline__ void dpp_key_max(uint32_t& lo, uint32_t& hi) {
  uint32_t olo = (uint32_t)dppmov<C>((int)lo);
  uint32_t ohi = (uint32_t)dppmov<C>((int)hi);
  bool bet = (ohi > hi) || (ohi == hi && olo > lo);
  lo = bet ? olo : lo;
  hi = bet ? ohi : hi;
}
__device__ __forceinline__ void wave_key_max_scal(uint32_t& lo, uint32_t& hi) {
  dpp_key_max<0x111>(lo, hi);
  dpp_key_max<0x112>(lo, hi);
  dpp_key_max<0x114>(lo, hi);
  dpp_key_max<0x118>(lo, hi);
  dpp_key_max<0x142>(lo, hi);
  dpp_key_max<0x143>(lo, hi);
  lo = (uint32_t)__builtin_amdgcn_readlane((int)lo, 63);
  hi = (uint32_t)__builtin_amdgcn_readlane((int)hi, 63);
}
template <int C>
__device__ __forceinline__ void dpp_key_min(uint32_t& lo, uint32_t& hi) {
  uint32_t olo = (uint32_t)dppmov<C>((int)lo);
  uint32_t ohi = (uint32_t)dppmov<C>((int)hi);
  bool bet = (ohi < hi) || (ohi == hi && olo < lo);
  lo = bet ? olo : lo;
  hi = bet ? ohi : hi;
}
__device__ __forceinline__ void wave_key_min_scal(uint32_t& lo, uint32_t& hi) {
  dpp_key_min<0x111>(lo, hi);
  dpp_key_min<0x112>(lo, hi);
  dpp_key_min<0x114>(lo, hi);
  dpp_key_min<0x118>(lo, hi);
  dpp_key_min<0x142>(lo, hi);
  dpp_key_min<0x143>(lo, hi);
  lo = (uint32_t)__builtin_amdgcn_readlane((int)lo, 63);
  hi = (uint32_t)__builtin_amdgcn_readlane((int)hi, 63);
}

// ---------------------------------------------------------------------------
// misc helpers
// ---------------------------------------------------------------------------
__device__ __forceinline__ uint32_t rotl32(uint32_t x, int d) {
  return (x << d) | (x >> (32 - d));
}

// threefry2x32 with key (0, 42) == jax.random.key(42)
__device__ __forceinline__ void threefry_0_42(uint32_t c0, uint32_t c1,
                                              uint32_t& o0, uint32_t& o1) {
  const uint32_t k0 = 0u, k1 = 42u;
  const uint32_t ks[3] = {k0, k1, k0 ^ k1 ^ 0x1BD11BDAu};
  uint32_t x0 = c0 + ks[0];
  uint32_t x1 = c1 + ks[1];
  const int R0[4] = {13, 15, 26, 6};
  const int R1[4] = {17, 29, 16, 24};
  #pragma unroll
  for (int g = 0; g < 5; ++g) {
    const int* R = (g & 1) ? R1 : R0;
    #pragma unroll
    for (int r = 0; r < 4; ++r) {
      x0 += x1;
      x1 = rotl32(x1, R[r]);
      x1 ^= x0;
    }
    x0 += ks[(g + 1) % 3];
    x1 += ks[(g + 2) % 3] + (uint32_t)(g + 1);
  }
  o0 = x0; o1 = x1;
}

// XLA/Giles single-precision erfinv (matches jax.lax.erf_inv f32 path)
__device__ __forceinline__ float erfinv_xla(float x) {
  float w = -log1pf(-x * x);
  float p;
  if (w < 5.0f) {
    w = w - 2.5f;
    p = 2.81022636e-08f;
    p = fmaf(p, w, 3.43273939e-07f);
    p = fmaf(p, w, -3.5233877e-06f);
    p = fmaf(p, w, -4.39150654e-06f);
    p = fmaf(p, w, 0.00021858087f);
    p = fmaf(p, w, -0.00125372503f);
    p = fmaf(p, w, -0.00417768164f);
    p = fmaf(p, w, 0.246640727f);
    p = fmaf(p, w, 1.50140941f);
  } else {
    w = sqrtf(w) - 3.0f;
    p = -0.000200214257f;
    p = fmaf(p, w, 0.000100950558f);
    p = fmaf(p, w, 0.00134934322f);
    p = fmaf(p, w, -0.00367342844f);
    p = fmaf(p, w, 0.00573950773f);
    p = fmaf(p, w, -0.0076224613f);
    p = fmaf(p, w, 0.00943887047f);
    p = fmaf(p, w, 1.00167406f);
    p = fmaf(p, w, 2.83297682f);
  }
  return p * x;
}

// ---------------------------------------------------------------------------
// kernel 1: transpose weight matrices into ws (WT[c][i] = W[i][c]) so the
// MLP inner loops read weights with wave-uniform (scalar) addresses.
// ---------------------------------------------------------------------------
__global__ __launch_bounds__(256) void prep_transpose(
    const float* __restrict__ a0, const float* __restrict__ a1,
    const float* __restrict__ a2, const float* __restrict__ a3,
    const float* __restrict__ a4, const float* __restrict__ a5,
    const float* __restrict__ a6, const float* __restrict__ a7,
    float* __restrict__ ws) {
  int u = blockIdx.x * 256 + threadIdx.x;
  if (u < 96)    { ws[O_WT1S1 + u] = a0[(u % 3)   * 32  + u / 3];   return; } u -= 96;
  if (u < 1024)  { ws[O_WT2S1 + u] = a1[(u % 32)  * 32  + u / 32];  return; } u -= 1024;
  if (u < 2048)  { ws[O_WT3S1 + u] = a2[(u % 32)  * 64  + u / 32];  return; } u -= 2048;
  if (u < 4288)  { ws[O_WT1S2 + u] = a3[(u % 67)  * 64  + u / 67];  return; } u -= 4288;
  if (u < 4096)  { ws[O_WT2S2 + u] = a4[(u % 64)  * 64  + u / 64];  return; } u -= 4096;
  if (u < 8192)  { ws[O_WT3S2 + u] = a5[(u % 64)  * 128 + u / 64];  return; } u -= 8192;
  if (u < 16768) { ws[O_WT1S3 + u] = a6[(u % 131) * 128 + u / 131]; return; } u -= 16768;
  if (u < 32768) { ws[O_WT2S3 + u] = a7[(u % 128) * 256 + u / 128]; return; }
}

// ---------------------------------------------------------------------------
// kernel 2/4: farthest point sampling. One block per batch, T=512 threads
// (2 waves/SIMD for latency hiding). Per iteration: distance+local argmax in
// registers -> ONE fused u64-key DPP ladder (d2bits<<32 | ~idx; exact,
// first-index ties) -> wave winner's coords fetched pre-barrier and posted
// with the key -> ONE barrier -> all threads select among NW candidates in
// registers (coords ride along; no post-barrier LDS dependency).
// Bit-exact vs reference: contraction-off distance, fmin update,
// first-index argmax.
// ---------------------------------------------------------------------------
template <int N, int M, int T>
__global__ __launch_bounds__(T) void fps_kernel(const float* __restrict__ pos,
                                                float* __restrict__ centers) {
  constexpr int PPT = N / T;
  constexpr int NW  = T / 64;
  __shared__ float4 ps[N];
  __shared__ float4 candA[2][NW];  // (keyHi bits, keyLo bits, x, y)
  __shared__ float  candZ[2][NW];
  const int tid  = threadIdx.x;
  const int lane = tid & 63;
  const int wid  = tid >> 6;
  const int b    = blockIdx.x;
  const float* pb = pos + (size_t)b * N * 3;

  float mx[PPT], my[PPT], mz[PPT], md[PPT];
  #pragma unroll
  for (int s = 0; s < PPT; ++s) {
    int i = s * T + tid;
    float x = pb[i * 3 + 0], y = pb[i * 3 + 1], z = pb[i * 3 + 2];
    ps[i] = make_float4(x, y, z, 0.0f);
    mx[s] = x; my[s] = y; mz[s] = z;
    md[s] = __builtin_inff();
  }
  __syncthreads();

  float4 c0 = ps[0];
  float cx = c0.x, cy = c0.y, cz = c0.z;
  float* cb = centers + (size_t)b * M * 3;

  for (int m = 0; m < M; ++m) {
    if (tid == 0) { cb[m * 3 + 0] = cx; cb[m * 3 + 1] = cy; cb[m * 3 + 2] = cz; }
    float bv = -1.0f;
    int   bi = 0x7FFFFFFF;
    {
      #pragma clang fp contract(off)
      #pragma unroll
      for (int s = 0; s < PPT; ++s) {
        float dx = mx[s] - cx, dy = my[s] - cy, dz = mz[s] - cz;
        float d = (dx * dx + dy * dy) + dz * dz;   // numpy order, no FMA
        float nd = fminf(md[s], d);
        md[s] = nd;
        if (nd > bv) { bv = nd; bi = s * T + tid; }  // strict > keeps lowest idx
      }
    }
    // exact wave argmax via one fused u64-key ladder (bv >= 0 always after
    // the first point, so f32 bits are monotone)
    uint32_t klo = ~(uint32_t)bi;
    uint32_t khi = __float_as_uint(bv);
    wave_key_max_scal(klo, khi);
    int p = (int)~klo;

    float4 cw = ps[p];             // wave-uniform broadcast read (pre-barrier)
    if (lane == 0) {
      candA[m & 1][wid] = make_float4(__uint_as_float(khi),
                                      __uint_as_float(klo), cw.x, cw.y);
      candZ[m & 1][wid] = cw.z;
    }
    __syncthreads();
    // all threads: select among NW candidates (registers, exact tie-break)
    float4 aw0 = candA[m & 1][0];
    uint32_t Khi = __float_as_uint(aw0.x), Klo = __float_as_uint(aw0.y);
    float wx = aw0.z, wy = aw0.w, wz = candZ[m & 1][0];
    #pragma unroll
    for (int w = 1; w < NW; ++w) {
      float4 aw = candA[m & 1][w];
      float zz = candZ[m & 1][w];
      uint32_t ohi = __float_as_uint(aw.x), olo = __float_as_uint(aw.y);
      bool bet = (ohi > Khi) || (ohi == Khi && olo > Klo);
      Khi = bet ? ohi : Khi;
      Klo = bet ? olo : Klo;
      wx  = bet ? aw.z : wx;
      wy  = bet ? aw.w : wy;
      wz  = bet ? zz   : wz;
    }
    cx = wx; cy = wy; cz = wz;
  }
}

// ---------------------------------------------------------------------------
// kernel 3/5: SA module. One wave (64 threads) per center.
// Phase 1: scan all points, ballot-compact in-radius candidates (d2, idx)
//          into LDS in point-index order (matches top_k tie-breaking).
// Phase 2: register-resident K=64 min-extraction: candidates prefetched to
//          VGPRs, per round a register min-scan + one fused u64-key-min DPP
//          ladder + compare-select invalidation (no LDS in the loop).
// Phase 3: MLP with lane<->neighbor; weights via wave-uniform loads from
//          transposed copies; 4-channel blocking for ILP; layer handoff
//          through per-lane LDS rows (float4 stores).
// Phase 4: DPP cross-lane max per channel -> coalesced row store.
// ---------------------------------------------------------------------------
template <int NPTS, int DF, int D1, int D2, int DOUT>
__global__ __launch_bounds__(64) void sa_kernel(
    const float* __restrict__ pts, const float* __restrict__ feats,
    const float* __restrict__ centers, float* __restrict__ outf,
    const float* __restrict__ wt1, const float* __restrict__ bz1,
    const float* __restrict__ wt2, const float* __restrict__ bz2,
    const float* __restrict__ wt3, const float* __restrict__ bz3,
    int M, float r2max) {
  constexpr int DIN = DF + 3;
  constexpr int S1  = D1 + 4;   // odd quad-stride: conflict-light b128 rows
  constexpr int S2  = D2 + 4;
  __shared__ float sd[CAP];
  __shared__ int   si[CAP];
  __shared__ float hb1[64 * S1];
  __shared__ float hb2[64 * S2];

  const int lane = threadIdx.x;
  const int bm = blockIdx.x;
  const int b = bm / M, m = bm % M;
  const float* pb = pts + (size_t)b * NPTS * 3;
  const float* cc = centers + ((size_t)b * M + m) * 3;
  const float cx = cc[0], cy = cc[1], cz = cc[2];

  // ---- phase 1: scan & compact
  int cnt = 0;
  const unsigned long long ltmask = (1ull << lane) - 1ull;
  for (int base = 0; base < NPTS; base += 64) {
    int i = base + lane;
    float x3 = pb[i * 3 + 0], y3 = pb[i * 3 + 1], z3 = pb[i * 3 + 2];
    float d2;
    {
      #pragma clang fp contract(off)
      float dx = cx - x3, dy = cy - y3, dz = cz - z3;
      d2 = (dx * dx + dy * dy) + dz * dz;
    }
    bool inr = (d2 <= r2max);
    unsigned long long mk = __ballot(inr);
    int p = cnt + (int)__popcll(mk & ltmask);
    if (inr && p < CAP) { sd[p] = d2; si[p] = i; }
    cnt += (int)__popcll(mk);
  }
  if (cnt > CAP) cnt = CAP;
  __syncthreads();

  // ---- phase 2: K-nearest selection (register-resident extraction)
  int my_nbr = -1;
  if (cnt <= KNB) {
    my_nbr = (lane < cnt) ? si[lane] : -1;
  } else {
    constexpr int SMAX = CAP / 64;
    float rd[SMAX];
    #pragma unroll
    for (int s = 0; s < SMAX; ++s) {
      rd[s] = __builtin_inff();
      if (s * 64 < cnt) {
        int q = s * 64 + lane;
        if (q < cnt) rd[s] = sd[q];
      }
    }
    for (int k = 0; k < KNB; ++k) {
      float bv = rd[0];
      int   bp = lane;
      #pragma unroll
      for (int s = 1; s < SMAX; ++s) {
        if (s * 64 < cnt) {
          if (rd[s] < bv) { bv = rd[s]; bp = s * 64 + lane; }
        }
      }
      uint32_t klo = (uint32_t)bp;
      uint32_t khi = __float_as_uint(bv);   // d2 >= 0: bits monotone
      wave_key_min_scal(klo, khi);
      int bpw = (int)klo;
      if (lane == k) my_nbr = si[bpw];
      // invalidate winner in owner lane (branchless compare-select)
      int wl = bpw & 63, wsl = bpw >> 6;
      #pragma unroll
      for (int s = 0; s < SMAX; ++s) {
        if (s * 64 < cnt) {
          rd[s] = (lane == wl && s == wsl) ? __builtin_inff() : rd[s];
        }
      }
    }
  }
  const bool valid = (my_nbr >= 0);
  const int safeN = valid ? my_nbr : 0;

  // ---- phase 3: build per-lane input
  float rel[3];
  {
    const float* pr = pb + (size_t)safeN * 3;
    rel[0] = pr[0] - cx; rel[1] = pr[1] - cy; rel[2] = pr[2] - cz;
  }
  float xin[DF > 0 ? DF : 1];
  if constexpr (DF > 0) {
    const float* xr = feats + ((size_t)b * NPTS + safeN) * DF;
    #pragma unroll
    for (int i = 0; i < DF; i += 4) {
      float4 v = *reinterpret_cast<const float4*>(xr + i);
      xin[i] = v.x; xin[i + 1] = v.y; xin[i + 2] = v.z; xin[i + 3] = v.w;
    }
  }

  // L1 -> per-lane LDS row (relu), 4-channel blocking
  float* r1 = hb1 + lane * S1;
  for (int c = 0; c < D1; c += 4) {
    const float* w0 = wt1 + (c + 0) * DIN;
    const float* w1 = wt1 + (c + 1) * DIN;
    const float* w2 = wt1 + (c + 2) * DIN;
    const float* w3 = wt1 + (c + 3) * DIN;
    float a0 = bz1[c + 0], a1 = bz1[c + 1], a2 = bz1[c + 2], a3 = bz1[c + 3];
    if constexpr (DF > 0) {
      #pragma unroll
      for (int i = 0; i < DF; ++i) {
        a0 = fmaf(xin[i], w0[i], a0);
        a1 = fmaf(xin[i], w1[i], a1);
        a2 = fmaf(xin[i], w2[i], a2);
        a3 = fmaf(xin[i], w3[i], a3);
      }
    }
    #pragma unroll
    for (int r = 0; r < 3; ++r) {
      a0 = fmaf(rel[r], w0[DF + r], a0);
      a1 = fmaf(rel[r], w1[DF + r], a1);
      a2 = fmaf(rel[r], w2[DF + r], a2);
      a3 = fmaf(rel[r], w3[DF + r], a3);
    }
    *reinterpret_cast<float4*>(r1 + c) =
        make_float4(fmaxf(a0, 0.0f), fmaxf(a1, 0.0f),
                    fmaxf(a2, 0.0f), fmaxf(a3, 0.0f));
  }
  float h1[D1];
  #pragma unroll
  for (int i = 0; i < D1; i += 4) {
    float4 v = *reinterpret_cast<const float4*>(r1 + i);
    h1[i] = v.x; h1[i + 1] = v.y; h1[i + 2] = v.z; h1[i + 3] = v.w;
  }

  // L2, 4-channel blocking
  float* rr2 = hb2 + lane * S2;
  for (int c = 0; c < D2; c += 4) {
    const float* w0 = wt2 + (c + 0) * D1;
    const float* w1 = wt2 + (c + 1) * D1;
    const float* w2 = wt2 + (c + 2) * D1;
    const float* w3 = wt2 + (c + 3) * D1;
    float a0 = bz2[c + 0], a1 = bz2[c + 1], a2 = bz2[c + 2], a3 = bz2[c + 3];
    #pragma unroll
    for (int i = 0; i < D1; ++i) {
      a0 = fmaf(h1[i], w0[i], a0);
      a1 = fmaf(h1[i], w1[i], a1);
      a2 = fmaf(h1[i], w2[i], a2);
      a3 = fmaf(h1[i], w3[i], a3);
    }
    *reinterpret_cast<float4*>(rr2 + c) =
        make_float4(fmaxf(a0, 0.0f), fmaxf(a1, 0.0f),
                    fmaxf(a2, 0.0f), fmaxf(a3, 0.0f));
  }
  float h2[D2];
  #pragma unroll
  for (int i = 0; i < D2; i += 4) {
    float4 v = *reinterpret_cast<const float4*>(rr2 + i);
    h2[i] = v.x; h2[i + 1] = v.y; h2[i + 2] = v.z; h2[i + 3] = v.w;
  }

  // L3 (no relu) + DPP cross-lane max per channel -> coalesced store.
  // 4-channel blocking: 4 independent fma chains + 4 interleaved ladders.
  float* orow = outf + ((size_t)b * M + m) * DOUT;
  #pragma unroll
  for (int u = 0; u < DOUT / 64; ++u) {
    float outv = 0.0f;
    for (int ccb = 0; ccb < 64; ccb += 4) {
      const int c = u * 64 + ccb;
      const float* w0 = wt3 + (c + 0) * D2;
      const float* w1 = wt3 + (c + 1) * D2;
      const float* w2 = wt3 + (c + 2) * D2;
      const float* w3 = wt3 + (c + 3) * D2;
      float a0 = bz3[c + 0], a1 = bz3[c + 1], a2 = bz3[c + 2], a3 = bz3[c + 3];
      #pragma unroll
      for (int i = 0; i < D2; ++i) {
        a0 = fmaf(h2[i], w0[i], a0);
        a1 = fmaf(h2[i], w1[i], a1);
        a2 = fmaf(h2[i], w2[i], a2);
        a3 = fmaf(h2[i], w3[i], a3);
      }
      const float NI = -__builtin_inff();
      float s0 = wave_fmax_scal(valid ? a0 : NI);
      float s1 = wave_fmax_scal(valid ? a1 : NI);
      float s2 = wave_fmax_scal(valid ? a2 : NI);
      float s3 = wave_fmax_scal(valid ? a3 : NI);
      if (lane == ccb + 0) outv = s0;
      if (lane == ccb + 1) outv = s1;
      if (lane == ccb + 2) outv = s2;
      if (lane == ccb + 3) outv = s3;
    }
    orow[u * 64 + lane] = outv;
  }
}

// ---------------------------------------------------------------------------
// kernel 6: SA3 layers 1+2 (131->128->256, relu both). lane<->point, 4 waves
// split the output channels; h1 handed off through shared LDS rows.
// h2 written to global ws for the L3 kernel.
// ---------------------------------------------------------------------------
__global__ __launch_bounds__(256) void sa3_l12_kernel(
    const float* __restrict__ x2, const float* __restrict__ pos2,
    const float* __restrict__ wt1, const float* __restrict__ bz1,
    const float* __restrict__ wt2, const float* __restrict__ bz2,
    float* __restrict__ h2g) {
  __shared__ float H[64 * 132];
  const int tid = threadIdx.x;
  const int lane = tid & 63, w = tid >> 6;
  const int b = blockIdx.x >> 3, tile = blockIdx.x & 7;
  const int pt = tile * 64 + lane;
  const float* xrow = x2 + ((size_t)b * 512 + pt) * 128;
  float* hrow = H + lane * 132;
  const int c0 = w * 32;

  float f[64];
  #pragma unroll
  for (int i = 0; i < 64; i += 4) {
    float4 v = *reinterpret_cast<const float4*>(xrow + i);
    f[i] = v.x; f[i + 1] = v.y; f[i + 2] = v.z; f[i + 3] = v.w;
  }
  for (int c = c0; c < c0 + 32; ++c) {
    const float* wv = wt1 + c * 131;
    float acc = bz1[c];
    #pragma unroll
    for (int i = 0; i < 64; ++i) acc = fmaf(f[i], wv[i], acc);
    hrow[c] = acc;   // partial
  }
  #pragma unroll
  for (int i = 0; i < 64; i += 4) {
    float4 v = *reinterpret_cast<const float4*>(xrow + 64 + i);
    f[i] = v.x; f[i + 1] = v.y; f[i + 2] = v.z; f[i + 3] = v.w;
  }
  float q0, q1, q2;
  {
    const float* pr = pos2 + ((size_t)b * 512 + pt) * 3;
    q0 = pr[0]; q1 = pr[1]; q2 = pr[2];
  }
  for (int c = c0; c < c0 + 32; ++c) {
    const float* wv = wt1 + c * 131 + 64;
    float acc = hrow[c];
    #pragma unroll
    for (int i = 0; i < 64; ++i) acc = fmaf(f[i], wv[i], acc);
    acc = fmaf(q0, wv[64], acc);
    acc = fmaf(q1, wv[65], acc);
    acc = fmaf(q2, wv[66], acc);
    hrow[c] = fmaxf(acc, 0.0f);   // relu
  }
  __syncthreads();

  float h[128];
  #pragma unroll
  for (int i = 0; i < 128; i += 4) {
    float4 v = *reinterpret_cast<const float4*>(hrow + i);
    h[i] = v.x; h[i + 1] = v.y; h[i + 2] = v.z; h[i + 3] = v.w;
  }
  float* grow = h2g + ((size_t)b * 512 + pt) * 256;
  const int c1 = w * 64;
  for (int c = c1; c < c1 + 64; ++c) {
    const float* wv = wt2 + c * 128;
    float acc = bz2[c];
    #pragma unroll
    for (int i = 0; i < 128; ++i) acc = fmaf(h[i], wv[i], acc);
    grow[c] = fmaxf(acc, 0.0f);   // relu
  }
}

// ---------------------------------------------------------------------------
// kernel 7: SA3 layer 3 (256->512, no relu) fused with per-tile max over
// points. thread<->channel, acc[16] (16-point tiles, no spill). h2 rows read
// with wave-uniform loads (scalarized); W3 read in original layout, coalesced.
// grid: 8 batches x 32 point-tiles x 2 channel-halves = 512 blocks.
// ---------------------------------------------------------------------------
__global__ __launch_bounds__(256) void sa3_l3_kernel(
    const float* __restrict__ h2g, const float* __restrict__ w3,
    const float* __restrict__ bz3, float* __restrict__ fpart) {
  const int tid = threadIdx.x;
  const int blk = blockIdx.x;
  const int b   = blk >> 6;
  const int t16 = (blk >> 1) & 31;
  const int cb  = blk & 1;
  const int c = cb * 256 + tid;
  const float* hbase = h2g + ((size_t)b * 512 + t16 * 16) * 256;

  float acc[16];
  #pragma unroll
  for (int j = 0; j < 16; ++j) acc[j] = 0.0f;

  for (int i0 = 0; i0 < 256; i0 += 8) {
    float wv[8];
    #pragma unroll
    for (int u = 0; u < 8; ++u) wv[u] = w3[(size_t)(i0 + u) * 512 + c];
    #pragma unroll
    for (int j = 0; j < 16; ++j) {
      const float* hr = hbase + (size_t)j * 256 + i0;
      #pragma unroll
      for (int u = 0; u < 8; ++u) acc[j] = fmaf(hr[u], wv[u], acc[j]);
    }
  }
  float mv = acc[0];
  #pragma unroll
  for (int j = 1; j < 16; ++j) mv = fmaxf(mv, acc[j]);
  fpart[((size_t)b * 32 + t16) * 512 + c] = mv + bz3[c];
}

// ---------------------------------------------------------------------------
// kernel 8: final — reduce partial maxes (32 tiles), mu/log_var heads
// (f64 accumulate), threefry eps (partitionable layout),
// z = mu + eps * exp(0.5*lv). out = [z | mu | lv], each [8][32].
// ---------------------------------------------------------------------------
__global__ __launch_bounds__(64) void final_kernel(
    const float* __restrict__ fpart,
    const float* __restrict__ wmu, const float* __restrict__ bmu,
    const float* __restrict__ wlv, const float* __restrict__ blv,
    float* __restrict__ outp) {
  __shared__ float feat[512];
  const int tid = threadIdx.x;
  const int b = blockIdx.x;
  for (int cidx = tid; cidx < 512; cidx += 64) {
    float mv = fpart[(size_t)b * 32 * 512 + cidx];
    #pragma unroll
    for (int t = 1; t < 32; ++t)
      mv = fmaxf(mv, fpart[((size_t)b * 32 + t) * 512 + cidx]);
    feat[cidx] = mv;
  }
  __syncthreads();
  if (tid < 32) {
    const int c = tid;
    double amu = 0.0, alv = 0.0;
    for (int i = 0; i < 512; ++i) {
      double fv = (double)feat[i];
      amu += fv * (double)wmu[i * 32 + c];
      alv += fv * (double)wlv[i * 32 + c];
    }
    float mu = (float)amu + bmu[c];
    float lv = (float)alv + blv[c];

    // jax_threefry_partitionable=True 32-bit path:
    // counts = iota(u64); bits[n] = o0 ^ o1 of threefry(key, (n>>32, n&mask))
    uint32_t n = (uint32_t)(b * 32 + c);
    uint32_t o0, o1;
    threefry_0_42(0u, n, o0, o1);
    uint32_t bits = o0 ^ o1;
    float fl = __uint_as_float((bits >> 9) | 0x3f800000u) - 1.0f;
    const float LO = -0.99999994039535522461f;  // nextafter(-1,0) in f32
    float u = fl * 2.0f + LO;                   // (hi-lo) rounds to exactly 2.0f
    u = fmaxf(LO, u);
    float eps = 1.4142135623730951f * erfinv_xla(u);
    float z = mu + eps * expf(0.5f * lv);

    outp[b * 32 + c] = z;
    outp[256 + b * 32 + c] = mu;
    outp[512 + b * 32 + c] = lv;
  }
}

// ---------------------------------------------------------------------------
// launcher
// ---------------------------------------------------------------------------
extern "C" void kernel_launch(void* const* d_in, const int* in_sizes, int n_in,
                              void* d_out, int out_size, void* d_ws, size_t ws_size,
                              hipStream_t stream) {
  (void)in_sizes; (void)n_in; (void)out_size; (void)ws_size;
  const float* pos  = (const float*)d_in[0];
  const float* s1w0 = (const float*)d_in[1];  const float* s1b0 = (const float*)d_in[2];
  const float* s1w1 = (const float*)d_in[3];  const float* s1b1 = (const float*)d_in[4];
  const float* s1w2 = (const float*)d_in[5];  const float* s1b2 = (const float*)d_in[6];
  const float* s2w0 = (const float*)d_in[7];  const float* s2b0 = (const float*)d_in[8];
  const float* s2w1 = (const float*)d_in[9];  const float* s2b1 = (const float*)d_in[10];
  const float* s2w2 = (const float*)d_in[11]; const float* s2b2 = (const float*)d_in[12];
  const float* s3w0 = (const float*)d_in[13]; const float* s3b0 = (const float*)d_in[14];
  const float* s3w1 = (const float*)d_in[15]; const float* s3b1 = (const float*)d_in[16];
  const float* s3w2 = (const float*)d_in[17]; const float* s3b2 = (const float*)d_in[18];
  const float* wmu  = (const float*)d_in[19]; const float* bmu  = (const float*)d_in[20];
  const float* wlv  = (const float*)d_in[21]; const float* blv  = (const float*)d_in[22];
  float* ws = (float*)d_ws;
  float* out = (float*)d_out;

  prep_transpose<<<271, 256, 0, stream>>>(s1w0, s1w1, s1w2, s2w0, s2w1, s2w2,
                                          s3w0, s3w1, ws);

  fps_kernel<NPT0, M1, 512><<<BATCH, 512, 0, stream>>>(pos, ws + O_POS1);

  sa_kernel<NPT0, 0, 32, 32, 64><<<BATCH * M1, 64, 0, stream>>>(
      pos, nullptr, ws + O_POS1, ws + O_X1,
      ws + O_WT1S1, s1b0, ws + O_WT2S1, s1b1, ws + O_WT3S1, s1b2,
      M1, 0.04f);   // f32(0.2*0.2 in double) == 0.04f

  fps_kernel<M1, M2, 512><<<BATCH, 512, 0, stream>>>(ws + O_POS1, ws + O_POS2);

  sa_kernel<M1, 64, 64, 64, 128><<<BATCH * M2, 64, 0, stream>>>(
      ws + O_POS1, ws + O_X1, ws + O_POS2, ws + O_X2,
      ws + O_WT1S2, s2b0, ws + O_WT2S2, s2b1, ws + O_WT3S2, s2b2,
      M2, 0.16f);   // f32(0.4*0.4 in double) == 0.16f

  sa3_l12_kernel<<<BATCH * 8, 256, 0, stream>>>(
      ws + O_X2, ws + O_POS2, ws + O_WT1S3, s3b0, ws + O_WT2S3, s3b1,
      ws + O_H2G);

  sa3_l3_kernel<<<BATCH * 64, 256, 0, stream>>>(ws + O_H2G, s3w2, s3b2,
                                                ws + O_FP);

  final_kernel<<<BATCH, 64, 0, stream>>>(ws + O_FP, wmu, bmu, wlv, blv, out);
}

// Round 6
// 3887.192 us; speedup vs baseline: 1.0597x; 1.0597x over previous
//
#include <hip/hip_runtime.h>
#include <cstdint>
#include <cstddef>

// ---------------------------------------------------------------------------
// PointNet++ (PointNetEnc) forward on MI355X.
//
// Pipeline-fused: FPS (8 producer blocks) + SA (consumer waves, one center
// per wave) run in ONE kernel with agent-scope release/acquire progress
// flags, hiding SA behind the serial FPS critical path.
//
// Exactness-critical parts (FPS argmax, radius test, top-K set) use
// contraction-free f32 matching numpy semantics; cross-lane argmax/argmin
// via fused u64-key DPP ladders with first-index tie-break. MLP uses fmaf
// (5e-2 tolerance). eps = jax.random.normal(key(42)) via threefry2x32
// (partitionable) + XLA erfinv.
// ---------------------------------------------------------------------------

constexpr int BATCH = 8;
constexpr int NPT0  = 4096;
constexpr int M1    = 2048;
constexpr int M2    = 512;
constexpr int KNB   = 64;
constexpr int CAP   = 1024;

// workspace layout (float offsets). H2G aliases X1; FP aliases X2.
constexpr size_t O_WT1S1 = 0;
constexpr size_t O_WT2S1 = 96;
constexpr size_t O_WT3S1 = 1120;
constexpr size_t O_WT1S2 = 3168;
constexpr size_t O_WT2S2 = 7456;
constexpr size_t O_WT3S2 = 11552;
constexpr size_t O_WT1S3 = 19744;
constexpr size_t O_WT2S3 = 36512;
constexpr size_t O_POS1  = 69280;    // [8][2048][3]
constexpr size_t O_X1    = 118432;   // [8][2048][64]
constexpr size_t O_POS2  = 1167008;  // [8][512][3]
constexpr size_t O_X2    = 1179296;  // [8][512][128]
constexpr size_t O_H2G   = O_X1;     // [8][512][256]
constexpr size_t O_FP    = O_X2;     // [8][32][512]
constexpr size_t O_PROG  = 1703584;  // 16 ints (prog1[8], prog2[8])

// ---------------------------------------------------------------------------
// DPP wave-reduction helpers
// ---------------------------------------------------------------------------
template <int C>
__device__ __forceinline__ int dppmov(int x) {
  return __builtin_amdgcn_update_dpp(x, x, C, 0xF, 0xF, false);
}

__device__ __forceinline__ float wave_fmax_scal(float x) {
  x = fmaxf(x, __int_as_float(dppmov<0x111>(__float_as_int(x))));
  x = fmaxf(x, __int_as_float(dppmov<0x112>(__float_as_int(x))));
  x = fmaxf(x, __int_as_float(dppmov<0x114>(__float_as_int(x))));
  x = fmaxf(x, __int_as_float(dppmov<0x118>(__float_as_int(x))));
  x = fmaxf(x, __int_as_float(dppmov<0x142>(__float_as_int(x))));
  x = fmaxf(x, __int_as_float(dppmov<0x143>(__float_as_int(x))));
  return __int_as_float(__builtin_amdgcn_readlane(__float_as_int(x), 63));
}

template <int C>
__device__ __forceinline__ void dpp_key_max(uint32_t& lo, uint32_t& hi) {
  uint32_t olo = (uint32_t)dppmov<C>((int)lo);
  uint32_t ohi = (uint32_t)dppmov<C>((int)hi);
  bool bet = (ohi > hi) || (ohi == hi && olo > lo);
  lo = bet ? olo : lo;
  hi = bet ? ohi : hi;
}
__device__ __forceinline__ void wave_key_max_scal(uint32_t& lo, uint32_t& hi) {
  dpp_key_max<0x111>(lo, hi);
  dpp_key_max<0x112>(lo, hi);
  dpp_key_max<0x114>(lo, hi);
  dpp_key_max<0x118>(lo, hi);
  dpp_key_max<0x142>(lo, hi);
  dpp_key_max<0x143>(lo, hi);
  lo = (uint32_t)__builtin_amdgcn_readlane((int)lo, 63);
  hi = (uint32_t)__builtin_amdgcn_readlane((int)hi, 63);
}
template <int C>
__device__ __forceinline__ void dpp_key_min(uint32_t& lo, uint32_t& hi) {
  uint32_t olo = (uint32_t)dppmov<C>((int)lo);
  uint32_t ohi = (uint32_t)dppmov<C>((int)hi);
  bool bet = (ohi < hi) || (ohi == hi && olo < lo);
  lo = bet ? olo : lo;
  hi = bet ? ohi : hi;
}
__device__ __forceinline__ void wave_key_min_scal(uint32_t& lo, uint32_t& hi) {
  dpp_key_min<0x111>(lo, hi);
  dpp_key_min<0x112>(lo, hi);
  dpp_key_min<0x114>(lo, hi);
  dpp_key_min<0x118>(lo, hi);
  dpp_key_min<0x142>(lo, hi);
  dpp_key_min<0x143>(lo, hi);
  lo = (uint32_t)__builtin_amdgcn_readlane((int)lo, 63);
  hi = (uint32_t)__builtin_amdgcn_readlane((int)hi, 63);
}

__device__ __forceinline__ void wave_lds_fence() {
  asm volatile("s_waitcnt lgkmcnt(0)" ::: "memory");
}

// ---------------------------------------------------------------------------
// misc helpers
// ---------------------------------------------------------------------------
__device__ __forceinline__ uint32_t rotl32(uint32_t x, int d) {
  return (x << d) | (x >> (32 - d));
}

__device__ __forceinline__ void threefry_0_42(uint32_t c0, uint32_t c1,
                                              uint32_t& o0, uint32_t& o1) {
  const uint32_t k0 = 0u, k1 = 42u;
  const uint32_t ks[3] = {k0, k1, k0 ^ k1 ^ 0x1BD11BDAu};
  uint32_t x0 = c0 + ks[0];
  uint32_t x1 = c1 + ks[1];
  const int R0[4] = {13, 15, 26, 6};
  const int R1[4] = {17, 29, 16, 24};
  #pragma unroll
  for (int g = 0; g < 5; ++g) {
    const int* R = (g & 1) ? R1 : R0;
    #pragma unroll
    for (int r = 0; r < 4; ++r) {
      x0 += x1;
      x1 = rotl32(x1, R[r]);
      x1 ^= x0;
    }
    x0 += ks[(g + 1) % 3];
    x1 += ks[(g + 2) % 3] + (uint32_t)(g + 1);
  }
  o0 = x0; o1 = x1;
}

__device__ __forceinline__ float erfinv_xla(float x) {
  float w = -log1pf(-x * x);
  float p;
  if (w < 5.0f) {
    w = w - 2.5f;
    p = 2.81022636e-08f;
    p = fmaf(p, w, 3.43273939e-07f);
    p = fmaf(p, w, -3.5233877e-06f);
    p = fmaf(p, w, -4.39150654e-06f);
    p = fmaf(p, w, 0.00021858087f);
    p = fmaf(p, w, -0.00125372503f);
    p = fmaf(p, w, -0.00417768164f);
    p = fmaf(p, w, 0.246640727f);
    p = fmaf(p, w, 1.50140941f);
  } else {
    w = sqrtf(w) - 3.0f;
    p = -0.000200214257f;
    p = fmaf(p, w, 0.000100950558f);
    p = fmaf(p, w, 0.00134934322f);
    p = fmaf(p, w, -0.00367342844f);
    p = fmaf(p, w, 0.00573950773f);
    p = fmaf(p, w, -0.0076224613f);
    p = fmaf(p, w, 0.00943887047f);
    p = fmaf(p, w, 1.00167406f);
    p = fmaf(p, w, 2.83297682f);
  }
  return p * x;
}

// ---------------------------------------------------------------------------
// kernel 1: weight transposes + progress-flag zeroing
// ---------------------------------------------------------------------------
__global__ __launch_bounds__(256) void prep_transpose(
    const float* __restrict__ a0, const float* __restrict__ a1,
    const float* __restrict__ a2, const float* __restrict__ a3,
    const float* __restrict__ a4, const float* __restrict__ a5,
    const float* __restrict__ a6, const float* __restrict__ a7,
    float* __restrict__ ws) {
  int u0 = blockIdx.x * 256 + threadIdx.x;
  if (u0 < 16) ((int*)(ws + O_PROG))[u0] = 0;
  int u = u0;
  if (u < 96)    { ws[O_WT1S1 + u] = a0[(u % 3)   * 32  + u / 3];   return; } u -= 96;
  if (u < 1024)  { ws[O_WT2S1 + u] = a1[(u % 32)  * 32  + u / 32];  return; } u -= 1024;
  if (u < 2048)  { ws[O_WT3S1 + u] = a2[(u % 32)  * 64  + u / 32];  return; } u -= 2048;
  if (u < 4288)  { ws[O_WT1S2 + u] = a3[(u % 67)  * 64  + u / 67];  return; } u -= 4288;
  if (u < 4096)  { ws[O_WT2S2 + u] = a4[(u % 64)  * 64  + u / 64];  return; } u -= 4096;
  if (u < 8192)  { ws[O_WT3S2 + u] = a5[(u % 64)  * 128 + u / 64];  return; } u -= 8192;
  if (u < 16768) { ws[O_WT1S3 + u] = a6[(u % 131) * 128 + u / 131]; return; } u -= 16768;
  if (u < 32768) { ws[O_WT2S3 + u] = a7[(u % 128) * 256 + u / 128]; return; }
}

// ---------------------------------------------------------------------------
// FPS body (producer). T=512 threads; bit-exact reference semantics.
// Publishes prog[b] = m+1 every 64 iterations (agent-scope release).
// ---------------------------------------------------------------------------
template <int N, int M, int T>
__device__ __forceinline__ void fps_body(const float* __restrict__ pos,
                                         float* __restrict__ centers,
                                         int* __restrict__ prog,
                                         char* smem, int b) {
  constexpr int PPT = N / T;
  constexpr int NW  = T / 64;
  float* px = (float*)smem;
  float* py = px + N;
  float* pz = py + N;
  float4* candA = (float4*)(pz + N);           // [2][NW]
  float*  candZ = (float*)(candA + 2 * NW);    // [2][NW]
  const int tid  = threadIdx.x;
  const int lane = tid & 63;
  const int wid  = tid >> 6;
  const float* pb = pos + (size_t)b * N * 3;

  float mx[PPT], my[PPT], mz[PPT], md[PPT];
  #pragma unroll
  for (int s = 0; s < PPT; ++s) {
    int i = s * T + tid;
    float x = pb[i * 3 + 0], y = pb[i * 3 + 1], z = pb[i * 3 + 2];
    px[i] = x; py[i] = y; pz[i] = z;
    mx[s] = x; my[s] = y; mz[s] = z;
    md[s] = __builtin_inff();
  }
  __syncthreads();

  float cx = px[0], cy = py[0], cz = pz[0];
  float* cb = centers + (size_t)b * M * 3;

  for (int m = 0; m < M; ++m) {
    if (tid == 0) {
      cb[m * 3 + 0] = cx; cb[m * 3 + 1] = cy; cb[m * 3 + 2] = cz;
      if ((m & 63) == 63)
        __hip_atomic_store(prog + b, m + 1, __ATOMIC_RELEASE,
                           __HIP_MEMORY_SCOPE_AGENT);
    }
    float bv = -1.0f;
    int   bi = 0x7FFFFFFF;
    {
      #pragma clang fp contract(off)
      #pragma unroll
      for (int s = 0; s < PPT; ++s) {
        float dx = mx[s] - cx, dy = my[s] - cy, dz = mz[s] - cz;
        float d = (dx * dx + dy * dy) + dz * dz;   // numpy order, no FMA
        float nd = fminf(md[s], d);
        md[s] = nd;
        if (nd > bv) { bv = nd; bi = s * T + tid; }
      }
    }
    uint32_t klo = ~(uint32_t)bi;
    uint32_t khi = __float_as_uint(bv);
    wave_key_max_scal(klo, khi);
    int p = (int)~klo;

    float wx = px[p], wy = py[p], wz = pz[p];   // pre-barrier broadcast reads
    if (lane == 0) {
      candA[(m & 1) * NW + wid] =
          make_float4(__uint_as_float(khi), __uint_as_float(klo), wx, wy);
      candZ[(m & 1) * NW + wid] = wz;
    }
    __syncthreads();
    float4 aw0 = candA[(m & 1) * NW + 0];
    uint32_t Khi = __float_as_uint(aw0.x), Klo = __float_as_uint(aw0.y);
    float sx = aw0.z, sy = aw0.w, sz = candZ[(m & 1) * NW + 0];
    #pragma unroll
    for (int w = 1; w < NW; ++w) {
      float4 aw = candA[(m & 1) * NW + w];
      float zz = candZ[(m & 1) * NW + w];
      uint32_t ohi = __float_as_uint(aw.x), olo = __float_as_uint(aw.y);
      bool bet = (ohi > Khi) || (ohi == Khi && olo > Klo);
      Khi = bet ? ohi : Khi;
      Klo = bet ? olo : Klo;
      sx  = bet ? aw.z : sx;
      sy  = bet ? aw.w : sy;
      sz  = bet ? zz   : sz;
    }
    cx = sx; cy = sy; cz = sz;
  }
}

// ---------------------------------------------------------------------------
// SA body (consumer). ONE WAVE per center; spin-waits on prog[b] > m.
// LDS: per-wave sd/si only (8 KB). MLP activations entirely in registers.
// ---------------------------------------------------------------------------
template <int NPTS, int DF, int D1, int D2, int DOUT, int MM>
__device__ __forceinline__ void sa_body(
    const float* __restrict__ pts, const float* __restrict__ feats,
    const float* __restrict__ centers, float* __restrict__ outf,
    const float* __restrict__ wt1, const float* __restrict__ bz1,
    const float* __restrict__ wt2, const float* __restrict__ bz2,
    const float* __restrict__ wt3, const float* __restrict__ bz3,
    float r2max, int* __restrict__ prog, char* smem) {
  constexpr int DIN = DF + 3;
  const int lane = threadIdx.x & 63;
  const int wid  = threadIdx.x >> 6;
  const int g = ((int)blockIdx.x - 8) * 8 + wid;
  const int b = g / MM, m = g % MM;
  float* sd = (float*)(smem + wid * 8192);
  int*   si = (int*)(smem + wid * 8192 + 4096);

  // ---- spin until center m is published
  for (;;) {
    int r = 0;
    if (lane == 0)
      r = __hip_atomic_load(prog + b, __ATOMIC_ACQUIRE,
                            __HIP_MEMORY_SCOPE_AGENT);
    r = __builtin_amdgcn_readfirstlane(r);
    if (r > m) break;
    __builtin_amdgcn_s_sleep(2);
  }
  __builtin_amdgcn_fence(__ATOMIC_ACQUIRE, "agent");

  const float* pb = pts + (size_t)b * NPTS * 3;
  const float* cc = centers + ((size_t)b * MM + m) * 3;
  const float cx = cc[0], cy = cc[1], cz = cc[2];

  // ---- phase 1: scan & ballot-compact
  int cnt = 0;
  const unsigned long long ltmask = (1ull << lane) - 1ull;
  for (int base = 0; base < NPTS; base += 64) {
    int i = base + lane;
    float x3 = pb[i * 3 + 0], y3 = pb[i * 3 + 1], z3 = pb[i * 3 + 2];
    float d2;
    {
      #pragma clang fp contract(off)
      float dx = cx - x3, dy = cy - y3, dz = cz - z3;
      d2 = (dx * dx + dy * dy) + dz * dz;
    }
    bool inr = (d2 <= r2max);
    unsigned long long mk = __ballot(inr);
    int p = cnt + (int)__popcll(mk & ltmask);
    if (inr && p < CAP) { sd[p] = d2; si[p] = i; }
    cnt += (int)__popcll(mk);
  }
  if (cnt > CAP) cnt = CAP;
  wave_lds_fence();

  // ---- phase 2: K-nearest (register-resident extraction, exact ties)
  int my_nbr = -1;
  if (cnt <= KNB) {
    my_nbr = (lane < cnt) ? si[lane] : -1;
  } else {
    constexpr int SMAX = CAP / 64;
    float rd[SMAX];
    #pragma unroll
    for (int s = 0; s < SMAX; ++s) {
      rd[s] = __builtin_inff();
      if (s * 64 < cnt) {
        int q = s * 64 + lane;
        if (q < cnt) rd[s] = sd[q];
      }
    }
    for (int k = 0; k < KNB; ++k) {
      float bv = rd[0];
      int   bp = lane;
      #pragma unroll
      for (int s = 1; s < SMAX; ++s) {
        if (s * 64 < cnt) {
          if (rd[s] < bv) { bv = rd[s]; bp = s * 64 + lane; }
        }
      }
      uint32_t klo = (uint32_t)bp;
      uint32_t khi = __float_as_uint(bv);
      wave_key_min_scal(klo, khi);
      int bpw = (int)klo;
      if (lane == k) my_nbr = si[bpw];
      int wl = bpw & 63, wsl = bpw >> 6;
      #pragma unroll
      for (int s = 0; s < SMAX; ++s) {
        if (s * 64 < cnt) {
          rd[s] = (lane == wl && s == wsl) ? __builtin_inff() : rd[s];
        }
      }
    }
  }
  const bool valid = (my_nbr >= 0);
  const int safeN = valid ? my_nbr : 0;

  // ---- phase 3: per-lane input
  float rel[3];
  {
    const float* pr = pb + (size_t)safeN * 3;
    rel[0] = pr[0] - cx; rel[1] = pr[1] - cy; rel[2] = pr[2] - cz;
  }
  float xin[DF > 0 ? DF : 1];
  if constexpr (DF > 0) {
    const float* xr = feats + ((size_t)b * NPTS + safeN) * DF;
    #pragma unroll
    for (int i = 0; i < DF; i += 4) {
      float4 v = *reinterpret_cast<const float4*>(xr + i);
      xin[i] = v.x; xin[i + 1] = v.y; xin[i + 2] = v.z; xin[i + 3] = v.w;
    }
  }

  // L1 (relu) — registers only, 4-channel blocking
  float h1[D1];
  for (int c = 0; c < D1; c += 4) {
    const float* w0 = wt1 + (c + 0) * DIN;
    const float* w1 = wt1 + (c + 1) * DIN;
    const float* w2 = wt1 + (c + 2) * DIN;
    const float* w3 = wt1 + (c + 3) * DIN;
    float a0 = bz1[c + 0], a1 = bz1[c + 1], a2 = bz1[c + 2], a3 = bz1[c + 3];
    if constexpr (DF > 0) {
      #pragma unroll
      for (int i = 0; i < DF; ++i) {
        a0 = fmaf(xin[i], w0[i], a0);
        a1 = fmaf(xin[i], w1[i], a1);
        a2 = fmaf(xin[i], w2[i], a2);
        a3 = fmaf(xin[i], w3[i], a3);
      }
    }
    #pragma unroll
    for (int r = 0; r < 3; ++r) {
      a0 = fmaf(rel[r], w0[DF + r], a0);
      a1 = fmaf(rel[r], w1[DF + r], a1);
      a2 = fmaf(rel[r], w2[DF + r], a2);
      a3 = fmaf(rel[r], w3[DF + r], a3);
    }
    h1[c + 0] = fmaxf(a0, 0.0f);
    h1[c + 1] = fmaxf(a1, 0.0f);
    h1[c + 2] = fmaxf(a2, 0.0f);
    h1[c + 3] = fmaxf(a3, 0.0f);
  }

  // L2 (relu)
  float h2[D2];
  for (int c = 0; c < D2; c += 4) {
    const float* w0 = wt2 + (c + 0) * D1;
    const float* w1 = wt2 + (c + 1) * D1;
    const float* w2 = wt2 + (c + 2) * D1;
    const float* w3 = wt2 + (c + 3) * D1;
    float a0 = bz2[c + 0], a1 = bz2[c + 1], a2 = bz2[c + 2], a3 = bz2[c + 3];
    #pragma unroll
    for (int i = 0; i < D1; ++i) {
      a0 = fmaf(h1[i], w0[i], a0);
      a1 = fmaf(h1[i], w1[i], a1);
      a2 = fmaf(h1[i], w2[i], a2);
      a3 = fmaf(h1[i], w3[i], a3);
    }
    h2[c + 0] = fmaxf(a0, 0.0f);
    h2[c + 1] = fmaxf(a1, 0.0f);
    h2[c + 2] = fmaxf(a2, 0.0f);
    h2[c + 3] = fmaxf(a3, 0.0f);
  }

  // L3 (no relu) + DPP max per channel -> coalesced store
  float* orow = outf + ((size_t)b * MM + m) * DOUT;
  #pragma unroll
  for (int u = 0; u < DOUT / 64; ++u) {
    float outv = 0.0f;
    for (int ccb = 0; ccb < 64; ccb += 4) {
      const int c = u * 64 + ccb;
      const float* w0 = wt3 + (c + 0) * D2;
      const float* w1 = wt3 + (c + 1) * D2;
      const float* w2 = wt3 + (c + 2) * D2;
      const float* w3 = wt3 + (c + 3) * D2;
      float a0 = bz3[c + 0], a1 = bz3[c + 1], a2 = bz3[c + 2], a3 = bz3[c + 3];
      #pragma unroll
      for (int i = 0; i < D2; ++i) {
        a0 = fmaf(h2[i], w0[i], a0);
        a1 = fmaf(h2[i], w1[i], a1);
        a2 = fmaf(h2[i], w2[i], a2);
        a3 = fmaf(h2[i], w3[i], a3);
      }
      const float NI = -__builtin_inff();
      float s0 = wave_fmax_scal(valid ? a0 : NI);
      float s1 = wave_fmax_scal(valid ? a1 : NI);
      float s2 = wave_fmax_scal(valid ? a2 : NI);
      float s3 = wave_fmax_scal(valid ? a3 : NI);
      if (lane == ccb + 0) outv = s0;
      if (lane == ccb + 1) outv = s1;
      if (lane == ccb + 2) outv = s2;
      if (lane == ccb + 3) outv = s3;
    }
    orow[u * 64 + lane] = outv;
  }
}

// ---------------------------------------------------------------------------
// stage A: fps1 (blocks 0..7) + sa1 (blocks 8.., 8 centers/block)
// stage B: fps2 + sa2
// ---------------------------------------------------------------------------
__global__ __launch_bounds__(512, 2) void stageA_kernel(
    const float* __restrict__ pos, float* __restrict__ ws,
    const float* __restrict__ bz1, const float* __restrict__ bz2,
    const float* __restrict__ bz3) {
  extern __shared__ char smem[];
  int* prog = (int*)(ws + O_PROG);
  if (blockIdx.x < 8) {
    asm volatile("s_setprio 3");
    fps_body<NPT0, M1, 512>(pos, ws + O_POS1, prog, smem, blockIdx.x);
  } else {
    sa_body<NPT0, 0, 32, 32, 64, M1>(
        pos, nullptr, ws + O_POS1, ws + O_X1,
        ws + O_WT1S1, bz1, ws + O_WT2S1, bz2, ws + O_WT3S1, bz3,
        0.04f, prog, smem);
  }
}

__global__ __launch_bounds__(512, 2) void stageB_kernel(
    float* __restrict__ ws,
    const float* __restrict__ bz1, const float* __restrict__ bz2,
    const float* __restrict__ bz3) {
  extern __shared__ char smem[];
  int* prog = (int*)(ws + O_PROG) + 8;
  if (blockIdx.x < 8) {
    asm volatile("s_setprio 3");
    fps_body<M1, M2, 512>(ws + O_POS1, ws + O_POS2, prog, smem, blockIdx.x);
  } else {
    sa_body<M1, 64, 64, 64, 128, M2>(
        ws + O_POS1, ws + O_X1, ws + O_POS2, ws + O_X2,
        ws + O_WT1S2, bz1, ws + O_WT2S2, bz2, ws + O_WT3S2, bz3,
        0.16f, prog, smem);
  }
}

// ---------------------------------------------------------------------------
// SA3 layers 1+2 (131->128->256)
// ---------------------------------------------------------------------------
__global__ __launch_bounds__(256) void sa3_l12_kernel(
    const float* __restrict__ x2, const float* __restrict__ pos2,
    const float* __restrict__ wt1, const float* __restrict__ bz1,
    const float* __restrict__ wt2, const float* __restrict__ bz2,
    float* __restrict__ h2g) {
  __shared__ float H[64 * 132];
  const int tid = threadIdx.x;
  const int lane = tid & 63, w = tid >> 6;
  const int b = blockIdx.x >> 3, tile = blockIdx.x & 7;
  const int pt = tile * 64 + lane;
  const float* xrow = x2 + ((size_t)b * 512 + pt) * 128;
  float* hrow = H + lane * 132;
  const int c0 = w * 32;

  float f[64];
  #pragma unroll
  for (int i = 0; i < 64; i += 4) {
    float4 v = *reinterpret_cast<const float4*>(xrow + i);
    f[i] = v.x; f[i + 1] = v.y; f[i + 2] = v.z; f[i + 3] = v.w;
  }
  for (int c = c0; c < c0 + 32; ++c) {
    const float* wv = wt1 + c * 131;
    float acc = bz1[c];
    #pragma unroll
    for (int i = 0; i < 64; ++i) acc = fmaf(f[i], wv[i], acc);
    hrow[c] = acc;
  }
  #pragma unroll
  for (int i = 0; i < 64; i += 4) {
    float4 v = *reinterpret_cast<const float4*>(xrow + 64 + i);
    f[i] = v.x; f[i + 1] = v.y; f[i + 2] = v.z; f[i + 3] = v.w;
  }
  float q0, q1, q2;
  {
    const float* pr = pos2 + ((size_t)b * 512 + pt) * 3;
    q0 = pr[0]; q1 = pr[1]; q2 = pr[2];
  }
  for (int c = c0; c < c0 + 32; ++c) {
    const float* wv = wt1 + c * 131 + 64;
    float acc = hrow[c];
    #pragma unroll
    for (int i = 0; i < 64; ++i) acc = fmaf(f[i], wv[i], acc);
    acc = fmaf(q0, wv[64], acc);
    acc = fmaf(q1, wv[65], acc);
    acc = fmaf(q2, wv[66], acc);
    hrow[c] = fmaxf(acc, 0.0f);
  }
  __syncthreads();

  float h[128];
  #pragma unroll
  for (int i = 0; i < 128; i += 4) {
    float4 v = *reinterpret_cast<const float4*>(hrow + i);
    h[i] = v.x; h[i + 1] = v.y; h[i + 2] = v.z; h[i + 3] = v.w;
  }
  float* grow = h2g + ((size_t)b * 512 + pt) * 256;
  const int c1 = w * 64;
  for (int c = c1; c < c1 + 64; ++c) {
    const float* wv = wt2 + c * 128;
    float acc = bz2[c];
    #pragma unroll
    for (int i = 0; i < 128; ++i) acc = fmaf(h[i], wv[i], acc);
    grow[c] = fmaxf(acc, 0.0f);
  }
}

// ---------------------------------------------------------------------------
// SA3 layer 3 (256->512) + per-tile max
// ---------------------------------------------------------------------------
__global__ __launch_bounds__(256) void sa3_l3_kernel(
    const float* __restrict__ h2g, const float* __restrict__ w3,
    const float* __restrict__ bz3, float* __restrict__ fpart) {
  const int tid = threadIdx.x;
  const int blk = blockIdx.x;
  const int b   = blk >> 6;
  const int t16 = (blk >> 1) & 31;
  const int cb  = blk & 1;
  const int c = cb * 256 + tid;
  const float* hbase = h2g + ((size_t)b * 512 + t16 * 16) * 256;

  float acc[16];
  #pragma unroll
  for (int j = 0; j < 16; ++j) acc[j] = 0.0f;

  for (int i0 = 0; i0 < 256; i0 += 8) {
    float wv[8];
    #pragma unroll
    for (int u = 0; u < 8; ++u) wv[u] = w3[(size_t)(i0 + u) * 512 + c];
    #pragma unroll
    for (int j = 0; j < 16; ++j) {
      const float* hr = hbase + (size_t)j * 256 + i0;
      #pragma unroll
      for (int u = 0; u < 8; ++u) acc[j] = fmaf(hr[u], wv[u], acc[j]);
    }
  }
  float mv = acc[0];
  #pragma unroll
  for (int j = 1; j < 16; ++j) mv = fmaxf(mv, acc[j]);
  fpart[((size_t)b * 32 + t16) * 512 + c] = mv + bz3[c];
}

// ---------------------------------------------------------------------------
// final
// ---------------------------------------------------------------------------
__global__ __launch_bounds__(64) void final_kernel(
    const float* __restrict__ fpart,
    const float* __restrict__ wmu, const float* __restrict__ bmu,
    const float* __restrict__ wlv, const float* __restrict__ blv,
    float* __restrict__ outp) {
  __shared__ float feat[512];
  const int tid = threadIdx.x;
  const int b = blockIdx.x;
  for (int cidx = tid; cidx < 512; cidx += 64) {
    float mv = fpart[(size_t)b * 32 * 512 + cidx];
    #pragma unroll
    for (int t = 1; t < 32; ++t)
      mv = fmaxf(mv, fpart[((size_t)b * 32 + t) * 512 + cidx]);
    feat[cidx] = mv;
  }
  __syncthreads();
  if (tid < 32) {
    const int c = tid;
    double amu = 0.0, alv = 0.0;
    for (int i = 0; i < 512; ++i) {
      double fv = (double)feat[i];
      amu += fv * (double)wmu[i * 32 + c];
      alv += fv * (double)wlv[i * 32 + c];
    }
    float mu = (float)amu + bmu[c];
    float lv = (float)alv + blv[c];

    uint32_t n = (uint32_t)(b * 32 + c);
    uint32_t o0, o1;
    threefry_0_42(0u, n, o0, o1);
    uint32_t bits = o0 ^ o1;
    float fl = __uint_as_float((bits >> 9) | 0x3f800000u) - 1.0f;
    const float LO = -0.99999994039535522461f;
    float u = fl * 2.0f + LO;
    u = fmaxf(LO, u);
    float eps = 1.4142135623730951f * erfinv_xla(u);
    float z = mu + eps * expf(0.5f * lv);

    outp[b * 32 + c] = z;
    outp[256 + b * 32 + c] = mu;
    outp[512 + b * 32 + c] = lv;
  }
}

// ---------------------------------------------------------------------------
// launcher
// ---------------------------------------------------------------------------
extern "C" void kernel_launch(void* const* d_in, const int* in_sizes, int n_in,
                              void* d_out, int out_size, void* d_ws, size_t ws_size,
                              hipStream_t stream) {
  (void)in_sizes; (void)n_in; (void)out_size; (void)ws_size;
  const float* pos  = (const float*)d_in[0];
  const float* s1w0 = (const float*)d_in[1];  const float* s1b0 = (const float*)d_in[2];
  const float* s1w1 = (const float*)d_in[3];  const float* s1b1 = (const float*)d_in[4];
  const float* s1w2 = (const float*)d_in[5];  const float* s1b2 = (const float*)d_in[6];
  const float* s2w0 = (const float*)d_in[7];  const float* s2b0 = (const float*)d_in[8];
  const float* s2w1 = (const float*)d_in[9];  const float* s2b1 = (const float*)d_in[10];
  const float* s2w2 = (const float*)d_in[11]; const float* s2b2 = (const float*)d_in[12];
  const float* s3w0 = (const float*)d_in[13]; const float* s3b0 = (const float*)d_in[14];
  const float* s3w1 = (const float*)d_in[15]; const float* s3b1 = (const float*)d_in[16];
  const float* s3w2 = (const float*)d_in[17]; const float* s3b2 = (const float*)d_in[18];
  const float* wmu  = (const float*)d_in[19]; const float* bmu  = (const float*)d_in[20];
  const float* wlv  = (const float*)d_in[21]; const float* blv  = (const float*)d_in[22];
  float* ws = (float*)d_ws;
  float* out = (float*)d_out;

  prep_transpose<<<271, 256, 0, stream>>>(s1w0, s1w1, s1w2, s2w0, s2w1, s2w2,
                                          s3w0, s3w1, ws);

  // stage A: fps1 + sa1 pipelined (8 producer blocks + 16384/8 consumer blocks)
  stageA_kernel<<<8 + (BATCH * M1) / 8, 512, 65536, stream>>>(
      pos, ws, s1b0, s1b1, s1b2);

  // stage B: fps2 + sa2 pipelined
  stageB_kernel<<<8 + (BATCH * M2) / 8, 512, 65536, stream>>>(
      ws, s2b0, s2b1, s2b2);

  sa3_l12_kernel<<<BATCH * 8, 256, 0, stream>>>(
      ws + O_X2, ws + O_POS2, ws + O_WT1S3, s3b0, ws + O_WT2S3, s3b1,
      ws + O_H2G);

  sa3_l3_kernel<<<BATCH * 64, 256, 0, stream>>>(ws + O_H2G, s3w2, s3b2,
                                                ws + O_FP);

  final_kernel<<<BATCH, 64, 0, stream>>>(ws + O_FP, wmu, bmu, wlv, blv, out);
}

// Round 7
// 3297.650 us; speedup vs baseline: 1.2491x; 1.1788x over previous
//
#include <hip/hip_runtime.h>
#include <cstdint>
#include <cstddef>

// ---------------------------------------------------------------------------
// PointNet++ (PointNetEnc) forward on MI355X.
//
// Pipeline-fused: FPS (8 producer blocks, barrier-free tag/slot mailbox
// sync) + SA (248 persistent consumer blocks, one wave per center, looping)
// in ONE kernel with agent-scope release/acquire progress flags.
//
// Exactness: FPS argmax / radius test / top-K set use contraction-free f32
// matching numpy semantics; cross-lane argmax/argmin via fused u64-key DPP
// ladders with first-index tie-break. MLP uses fmaf (5e-2 tolerance).
// eps = jax.random.normal(key(42)) via threefry2x32 (partitionable) + XLA
// erfinv.
// ---------------------------------------------------------------------------

constexpr int BATCH = 8;
constexpr int NPT0  = 4096;
constexpr int M1    = 2048;
constexpr int M2    = 512;
constexpr int KNB   = 64;
constexpr int CAP   = 1024;
constexpr int NCONS = 248;           // consumer blocks per stage

// workspace layout (float offsets). H2G aliases X1; FP aliases X2.
constexpr size_t O_WT1S1 = 0;
constexpr size_t O_WT2S1 = 96;
constexpr size_t O_WT3S1 = 1120;
constexpr size_t O_WT1S2 = 3168;
constexpr size_t O_WT2S2 = 7456;
constexpr size_t O_WT3S2 = 11552;
constexpr size_t O_WT1S3 = 19744;
constexpr size_t O_WT2S3 = 36512;
constexpr size_t O_POS1  = 69280;    // [8][2048][3]
constexpr size_t O_X1    = 118432;   // [8][2048][64]
constexpr size_t O_POS2  = 1167008;  // [8][512][3]
constexpr size_t O_X2    = 1179296;  // [8][512][128]
constexpr size_t O_H2G   = O_X1;     // [8][512][256]
constexpr size_t O_FP    = O_X2;     // [8][32][512]
constexpr size_t O_PROG  = 1703584;  // 16 ints (prog1[8], prog2[8])

// ---------------------------------------------------------------------------
// DPP wave-reduction helpers
// ---------------------------------------------------------------------------
template <int C>
__device__ __forceinline__ int dppmov(int x) {
  return __builtin_amdgcn_update_dpp(x, x, C, 0xF, 0xF, false);
}

__device__ __forceinline__ float wave_fmax_scal(float x) {
  x = fmaxf(x, __int_as_float(dppmov<0x111>(__float_as_int(x))));
  x = fmaxf(x, __int_as_float(dppmov<0x112>(__float_as_int(x))));
  x = fmaxf(x, __int_as_float(dppmov<0x114>(__float_as_int(x))));
  x = fmaxf(x, __int_as_float(dppmov<0x118>(__float_as_int(x))));
  x = fmaxf(x, __int_as_float(dppmov<0x142>(__float_as_int(x))));
  x = fmaxf(x, __int_as_float(dppmov<0x143>(__float_as_int(x))));
  return __int_as_float(__builtin_amdgcn_readlane(__float_as_int(x), 63));
}

template <int C>
__device__ __forceinline__ void dpp_key_max(uint32_t& lo, uint32_t& hi) {
  uint32_t olo = (uint32_t)dppmov<C>((int)lo);
  uint32_t ohi = (uint32_t)dppmov<C>((int)hi);
  bool bet = (ohi > hi) || (ohi == hi && olo > lo);
  lo = bet ? olo : lo;
  hi = bet ? ohi : hi;
}
__device__ __forceinline__ void wave_key_max_scal(uint32_t& lo, uint32_t& hi) {
  dpp_key_max<0x111>(lo, hi);
  dpp_key_max<0x112>(lo, hi);
  dpp_key_max<0x114>(lo, hi);
  dpp_key_max<0x118>(lo, hi);
  dpp_key_max<0x142>(lo, hi);
  dpp_key_max<0x143>(lo, hi);
  lo = (uint32_t)__builtin_amdgcn_readlane((int)lo, 63);
  hi = (uint32_t)__builtin_amdgcn_readlane((int)hi, 63);
}
template <int C>
__device__ __forceinline__ void dpp_key_min(uint32_t& lo, uint32_t& hi) {
  uint32_t olo = (uint32_t)dppmov<C>((int)lo);
  uint32_t ohi = (uint32_t)dppmov<C>((int)hi);
  bool bet = (ohi < hi) || (ohi == hi && olo < lo);
  lo = bet ? olo : lo;
  hi = bet ? ohi : hi;
}
__device__ __forceinline__ void wave_key_min_scal(uint32_t& lo, uint32_t& hi) {
  dpp_key_min<0x111>(lo, hi);
  dpp_key_min<0x112>(lo, hi);
  dpp_key_min<0x114>(lo, hi);
  dpp_key_min<0x118>(lo, hi);
  dpp_key_min<0x142>(lo, hi);
  dpp_key_min<0x143>(lo, hi);
  lo = (uint32_t)__builtin_amdgcn_readlane((int)lo, 63);
  hi = (uint32_t)__builtin_amdgcn_readlane((int)hi, 63);
}

__device__ __forceinline__ void wave_lds_fence() {
  asm volatile("s_waitcnt lgkmcnt(0)" ::: "memory");
}

// ---------------------------------------------------------------------------
// misc helpers
// ---------------------------------------------------------------------------
__device__ __forceinline__ uint32_t rotl32(uint32_t x, int d) {
  return (x << d) | (x >> (32 - d));
}

__device__ __forceinline__ void threefry_0_42(uint32_t c0, uint32_t c1,
                                              uint32_t& o0, uint32_t& o1) {
  const uint32_t k0 = 0u, k1 = 42u;
  const uint32_t ks[3] = {k0, k1, k0 ^ k1 ^ 0x1BD11BDAu};
  uint32_t x0 = c0 + ks[0];
  uint32_t x1 = c1 + ks[1];
  const int R0[4] = {13, 15, 26, 6};
  const int R1[4] = {17, 29, 16, 24};
  #pragma unroll
  for (int g = 0; g < 5; ++g) {
    const int* R = (g & 1) ? R1 : R0;
    #pragma unroll
    for (int r = 0; r < 4; ++r) {
      x0 += x1;
      x1 = rotl32(x1, R[r]);
      x1 ^= x0;
    }
    x0 += ks[(g + 1) % 3];
    x1 += ks[(g + 2) % 3] + (uint32_t)(g + 1);
  }
  o0 = x0; o1 = x1;
}

__device__ __forceinline__ float erfinv_xla(float x) {
  float w = -log1pf(-x * x);
  float p;
  if (w < 5.0f) {
    w = w - 2.5f;
    p = 2.81022636e-08f;
    p = fmaf(p, w, 3.43273939e-07f);
    p = fmaf(p, w, -3.5233877e-06f);
    p = fmaf(p, w, -4.39150654e-06f);
    p = fmaf(p, w, 0.00021858087f);
    p = fmaf(p, w, -0.00125372503f);
    p = fmaf(p, w, -0.00417768164f);
    p = fmaf(p, w, 0.246640727f);
    p = fmaf(p, w, 1.50140941f);
  } else {
    w = sqrtf(w) - 3.0f;
    p = -0.000200214257f;
    p = fmaf(p, w, 0.000100950558f);
    p = fmaf(p, w, 0.00134934322f);
    p = fmaf(p, w, -0.00367342844f);
    p = fmaf(p, w, 0.00573950773f);
    p = fmaf(p, w, -0.0076224613f);
    p = fmaf(p, w, 0.00943887047f);
    p = fmaf(p, w, 1.00167406f);
    p = fmaf(p, w, 2.83297682f);
  }
  return p * x;
}

// ---------------------------------------------------------------------------
// kernel 1: weight transposes + progress-flag zeroing
// ---------------------------------------------------------------------------
__global__ __launch_bounds__(256) void prep_transpose(
    const float* __restrict__ a0, const float* __restrict__ a1,
    const float* __restrict__ a2, const float* __restrict__ a3,
    const float* __restrict__ a4, const float* __restrict__ a5,
    const float* __restrict__ a6, const float* __restrict__ a7,
    float* __restrict__ ws) {
  int u0 = blockIdx.x * 256 + threadIdx.x;
  if (u0 < 16) ((int*)(ws + O_PROG))[u0] = 0;
  int u = u0;
  if (u < 96)    { ws[O_WT1S1 + u] = a0[(u % 3)   * 32  + u / 3];   return; } u -= 96;
  if (u < 1024)  { ws[O_WT2S1 + u] = a1[(u % 32)  * 32  + u / 32];  return; } u -= 1024;
  if (u < 2048)  { ws[O_WT3S1 + u] = a2[(u % 32)  * 64  + u / 32];  return; } u -= 2048;
  if (u < 4288)  { ws[O_WT1S2 + u] = a3[(u % 67)  * 64  + u / 67];  return; } u -= 4288;
  if (u < 4096)  { ws[O_WT2S2 + u] = a4[(u % 64)  * 64  + u / 64];  return; } u -= 4096;
  if (u < 8192)  { ws[O_WT3S2 + u] = a5[(u % 64)  * 128 + u / 64];  return; } u -= 8192;
  if (u < 16768) { ws[O_WT1S3 + u] = a6[(u % 131) * 128 + u / 131]; return; } u -= 16768;
  if (u < 32768) { ws[O_WT2S3 + u] = a7[(u % 128) * 256 + u / 128]; return; }
}

// ---------------------------------------------------------------------------
// FPS body (producer). T=256, 4 waves, BARRIER-FREE: per-wave tag/slot
// mailboxes in LDS (monotonic tags + parity double-buffered data slots,
// workgroup release/acquire fences). Bit-exact reference semantics.
// Publishes prog[b] = m+1 every 64 iterations (agent-scope release).
// ---------------------------------------------------------------------------
template <int N, int M>
__device__ __forceinline__ void fps_body(const float* __restrict__ pos,
                                         float* __restrict__ centers,
                                         int* __restrict__ prog,
                                         char* smem, int b) {
  constexpr int T   = 256;
  constexpr int PPT = N / T;
  constexpr int NW  = 4;
  float* px = (float*)smem;
  float* py = px + N;
  float* pz = py + N;
  int*    tags  = (int*)(pz + N);              // [8] (4 used, 4 pad)
  float4* slotA = (float4*)(tags + 8);         // [2][NW] (keyHi,keyLo,x,y)
  float*  slotZ = (float*)(slotA + 2 * NW);    // [2][NW]
  const int tid  = threadIdx.x;
  const int lane = tid & 63;
  const int wid  = tid >> 6;
  const float* pb = pos + (size_t)b * N * 3;

  if (tid < 8) tags[tid] = -1;

  float mx[PPT], my[PPT], mz[PPT], md[PPT];
  #pragma unroll
  for (int s = 0; s < PPT; ++s) {
    int i = s * T + tid;
    float x = pb[i * 3 + 0], y = pb[i * 3 + 1], z = pb[i * 3 + 2];
    px[i] = x; py[i] = y; pz[i] = z;
    mx[s] = x; my[s] = y; mz[s] = z;
    md[s] = __builtin_inff();
  }
  __syncthreads();

  float cx = px[0], cy = py[0], cz = pz[0];
  float* cb = centers + (size_t)b * M * 3;

  for (int m = 0; m < M; ++m) {
    if (tid == 0) {
      cb[m * 3 + 0] = cx; cb[m * 3 + 1] = cy; cb[m * 3 + 2] = cz;
      if ((m & 63) == 63)
        __hip_atomic_store(prog + b, m + 1, __ATOMIC_RELEASE,
                           __HIP_MEMORY_SCOPE_AGENT);
    }
    float bv = -1.0f;
    int   bi = 0x7FFFFFFF;
    {
      #pragma clang fp contract(off)
      #pragma unroll
      for (int s = 0; s < PPT; ++s) {
        float dx = mx[s] - cx, dy = my[s] - cy, dz = mz[s] - cz;
        float d = (dx * dx + dy * dy) + dz * dz;   // numpy order, no FMA
        float nd = fminf(md[s], d);
        md[s] = nd;
        if (nd > bv) { bv = nd; bi = s * T + tid; }
      }
    }
    uint32_t klo = ~(uint32_t)bi;
    uint32_t khi = __float_as_uint(bv);
    wave_key_max_scal(klo, khi);
    int p = (int)~klo;

    float wx = px[p], wy = py[p], wz = pz[p];   // wave-uniform broadcast
    const int par = (m & 1) * NW;
    if (lane == 0) {
      slotA[par + wid] =
          make_float4(__uint_as_float(khi), __uint_as_float(klo), wx, wy);
      slotZ[par + wid] = wz;
    }
    // release: data slots visible before tag bump
    __builtin_amdgcn_fence(__ATOMIC_RELEASE, "workgroup");
    if (lane == 0)
      __hip_atomic_store(&tags[wid], m, __ATOMIC_RELAXED,
                         __HIP_MEMORY_SCOPE_WORKGROUP);
    // poll all 4 tags (wave-uniform broadcast reads)
    for (;;) {
      int t0 = __hip_atomic_load(&tags[0], __ATOMIC_RELAXED,
                                 __HIP_MEMORY_SCOPE_WORKGROUP);
      int t1 = __hip_atomic_load(&tags[1], __ATOMIC_RELAXED,
                                 __HIP_MEMORY_SCOPE_WORKGROUP);
      int t2 = __hip_atomic_load(&tags[2], __ATOMIC_RELAXED,
                                 __HIP_MEMORY_SCOPE_WORKGROUP);
      int t3 = __hip_atomic_load(&tags[3], __ATOMIC_RELAXED,
                                 __HIP_MEMORY_SCOPE_WORKGROUP);
      int tmin = min(min(t0, t1), min(t2, t3));
      if (tmin >= m) break;
    }
    __builtin_amdgcn_fence(__ATOMIC_ACQUIRE, "workgroup");

    float4 aw0 = slotA[par + 0];
    uint32_t Khi = __float_as_uint(aw0.x), Klo = __float_as_uint(aw0.y);
    float sx = aw0.z, sy = aw0.w, sz = slotZ[par + 0];
    #pragma unroll
    for (int w = 1; w < NW; ++w) {
      float4 aw = slotA[par + w];
      float zz = slotZ[par + w];
      uint32_t ohi = __float_as_uint(aw.x), olo = __float_as_uint(aw.y);
      bool bet = (ohi > Khi) || (ohi == Khi && olo > Klo);
      Khi = bet ? ohi : Khi;
      Klo = bet ? olo : Klo;
      sx  = bet ? aw.z : sx;
      sy  = bet ? aw.w : sy;
      sz  = bet ? zz   : sz;
    }
    cx = sx; cy = sy; cz = sz;
  }
}

// ---------------------------------------------------------------------------
// SA body (persistent consumer). One wave per center, looping:
// wave g handles (b = g&7, m = g>>3 + k*248). Adaptive-sleep spin on prog.
// LDS: per-wave sd/si (8 KB). MLP activations entirely in registers.
// ---------------------------------------------------------------------------
template <int NPTS, int DF, int D1, int D2, int DOUT, int MM>
__device__ __forceinline__ void sa_body(
    const float* __restrict__ pts, const float* __restrict__ feats,
    const float* __restrict__ centers, float* __restrict__ outf,
    const float* __restrict__ wt1, const float* __restrict__ bz1,
    const float* __restrict__ wt2, const float* __restrict__ bz2,
    const float* __restrict__ wt3, const float* __restrict__ bz3,
    float r2max, int* __restrict__ prog, char* smem) {
  constexpr int DIN = DF + 3;
  const int lane = threadIdx.x & 63;
  const int wid  = threadIdx.x >> 6;
  const int g0 = ((int)blockIdx.x - 8) * 8 + wid;   // 0..1983
  const int b = g0 & 7;
  const int mbase = g0 >> 3;                        // 0..247
  float* sd = (float*)(smem + wid * 8192);
  int*   si = (int*)(smem + wid * 8192 + 4096);
  const float* pb = pts + (size_t)b * NPTS * 3;

  for (int m = mbase; m < MM; m += NCONS) {
    // ---- spin until center m is published (adaptive sleep)
    for (;;) {
      int r = 0;
      if (lane == 0)
        r = __hip_atomic_load(prog + b, __ATOMIC_ACQUIRE,
                              __HIP_MEMORY_SCOPE_AGENT);
      r = __builtin_amdgcn_readfirstlane(r);
      if (r > m) break;
      if (m - r > 128) __builtin_amdgcn_s_sleep(64);
      else             __builtin_amdgcn_s_sleep(4);
    }
    __builtin_amdgcn_fence(__ATOMIC_ACQUIRE, "agent");

    const float* cc = centers + ((size_t)b * MM + m) * 3;
    const float cx = cc[0], cy = cc[1], cz = cc[2];

    // ---- phase 1: scan & ballot-compact
    int cnt = 0;
    const unsigned long long ltmask = (1ull << lane) - 1ull;
    for (int base = 0; base < NPTS; base += 64) {
      int i = base + lane;
      float x3 = pb[i * 3 + 0], y3 = pb[i * 3 + 1], z3 = pb[i * 3 + 2];
      float d2;
      {
        #pragma clang fp contract(off)
        float dx = cx - x3, dy = cy - y3, dz = cz - z3;
        d2 = (dx * dx + dy * dy) + dz * dz;
      }
      bool inr = (d2 <= r2max);
      unsigned long long mk = __ballot(inr);
      int p = cnt + (int)__popcll(mk & ltmask);
      if (inr && p < CAP) { sd[p] = d2; si[p] = i; }
      cnt += (int)__popcll(mk);
    }
    if (cnt > CAP) cnt = CAP;
    wave_lds_fence();

    // ---- phase 2: K-nearest (register-resident extraction, exact ties)
    int my_nbr = -1;
    if (cnt <= KNB) {
      my_nbr = (lane < cnt) ? si[lane] : -1;
    } else {
      constexpr int SMAX = CAP / 64;
      float rd[SMAX];
      #pragma unroll
      for (int s = 0; s < SMAX; ++s) {
        rd[s] = __builtin_inff();
        if (s * 64 < cnt) {
          int q = s * 64 + lane;
          if (q < cnt) rd[s] = sd[q];
        }
      }
      for (int k = 0; k < KNB; ++k) {
        float bv = rd[0];
        int   bp = lane;
        #pragma unroll
        for (int s = 1; s < SMAX; ++s) {
          if (s * 64 < cnt) {
            if (rd[s] < bv) { bv = rd[s]; bp = s * 64 + lane; }
          }
        }
        uint32_t klo = (uint32_t)bp;
        uint32_t khi = __float_as_uint(bv);
        wave_key_min_scal(klo, khi);
        int bpw = (int)klo;
        if (lane == k) my_nbr = si[bpw];
        int wl = bpw & 63, wsl = bpw >> 6;
        #pragma unroll
        for (int s = 0; s < SMAX; ++s) {
          if (s * 64 < cnt) {
            rd[s] = (lane == wl && s == wsl) ? __builtin_inff() : rd[s];
          }
        }
      }
    }
    const bool valid = (my_nbr >= 0);
    const int safeN = valid ? my_nbr : 0;

    // ---- phase 3: per-lane input
    float rel[3];
    {
      const float* pr = pb + (size_t)safeN * 3;
      rel[0] = pr[0] - cx; rel[1] = pr[1] - cy; rel[2] = pr[2] - cz;
    }
    float xin[DF > 0 ? DF : 1];
    if constexpr (DF > 0) {
      const float* xr = feats + ((size_t)b * NPTS + safeN) * DF;
      #pragma unroll
      for (int i = 0; i < DF; i += 4) {
        float4 v = *reinterpret_cast<const float4*>(xr + i);
        xin[i] = v.x; xin[i + 1] = v.y; xin[i + 2] = v.z; xin[i + 3] = v.w;
      }
    }

    // L1 (relu) — registers only, 4-channel blocking
    float h1[D1];
    for (int c = 0; c < D1; c += 4) {
      const float* w0 = wt1 + (c + 0) * DIN;
      const float* w1 = wt1 + (c + 1) * DIN;
      const float* w2 = wt1 + (c + 2) * DIN;
      const float* w3 = wt1 + (c + 3) * DIN;
      float a0 = bz1[c + 0], a1 = bz1[c + 1], a2 = bz1[c + 2], a3 = bz1[c + 3];
      if constexpr (DF > 0) {
        #pragma unroll
        for (int i = 0; i < DF; ++i) {
          a0 = fmaf(xin[i], w0[i], a0);
          a1 = fmaf(xin[i], w1[i], a1);
          a2 = fmaf(xin[i], w2[i], a2);
          a3 = fmaf(xin[i], w3[i], a3);
        }
      }
      #pragma unroll
      for (int r = 0; r < 3; ++r) {
        a0 = fmaf(rel[r], w0[DF + r], a0);
        a1 = fmaf(rel[r], w1[DF + r], a1);
        a2 = fmaf(rel[r], w2[DF + r], a2);
        a3 = fmaf(rel[r], w3[DF + r], a3);
      }
      h1[c + 0] = fmaxf(a0, 0.0f);
      h1[c + 1] = fmaxf(a1, 0.0f);
      h1[c + 2] = fmaxf(a2, 0.0f);
      h1[c + 3] = fmaxf(a3, 0.0f);
    }

    // L2 (relu)
    float h2[D2];
    for (int c = 0; c < D2; c += 4) {
      const float* w0 = wt2 + (c + 0) * D1;
      const float* w1 = wt2 + (c + 1) * D1;
      const float* w2 = wt2 + (c + 2) * D1;
      const float* w3 = wt2 + (c + 3) * D1;
      float a0 = bz2[c + 0], a1 = bz2[c + 1], a2 = bz2[c + 2], a3 = bz2[c + 3];
      #pragma unroll
      for (int i = 0; i < D1; ++i) {
        a0 = fmaf(h1[i], w0[i], a0);
        a1 = fmaf(h1[i], w1[i], a1);
        a2 = fmaf(h1[i], w2[i], a2);
        a3 = fmaf(h1[i], w3[i], a3);
      }
      h2[c + 0] = fmaxf(a0, 0.0f);
      h2[c + 1] = fmaxf(a1, 0.0f);
      h2[c + 2] = fmaxf(a2, 0.0f);
      h2[c + 3] = fmaxf(a3, 0.0f);
    }

    // L3 (no relu) + DPP max per channel -> coalesced store
    float* orow = outf + ((size_t)b * MM + m) * DOUT;
    #pragma unroll
    for (int u = 0; u < DOUT / 64; ++u) {
      float outv = 0.0f;
      for (int ccb = 0; ccb < 64; ccb += 4) {
        const int c = u * 64 + ccb;
        const float* w0 = wt3 + (c + 0) * D2;
        const float* w1 = wt3 + (c + 1) * D2;
        const float* w2 = wt3 + (c + 2) * D2;
        const float* w3 = wt3 + (c + 3) * D2;
        float a0 = bz3[c + 0], a1 = bz3[c + 1], a2 = bz3[c + 2], a3 = bz3[c + 3];
        #pragma unroll
        for (int i = 0; i < D2; ++i) {
          a0 = fmaf(h2[i], w0[i], a0);
          a1 = fmaf(h2[i], w1[i], a1);
          a2 = fmaf(h2[i], w2[i], a2);
          a3 = fmaf(h2[i], w3[i], a3);
        }
        const float NI = -__builtin_inff();
        float s0 = wave_fmax_scal(valid ? a0 : NI);
        float s1 = wave_fmax_scal(valid ? a1 : NI);
        float s2 = wave_fmax_scal(valid ? a2 : NI);
        float s3 = wave_fmax_scal(valid ? a3 : NI);
        if (lane == ccb + 0) outv = s0;
        if (lane == ccb + 1) outv = s1;
        if (lane == ccb + 2) outv = s2;
        if (lane == ccb + 3) outv = s3;
      }
      orow[u * 64 + lane] = outv;
    }
  }
}

// ---------------------------------------------------------------------------
// stage A: fps1 (blocks 0..7) + sa1 (248 persistent consumer blocks)
// stage B: fps2 + sa2
// ---------------------------------------------------------------------------
__global__ __launch_bounds__(512, 2) void stageA_kernel(
    const float* __restrict__ pos, float* __restrict__ ws,
    const float* __restrict__ bz1, const float* __restrict__ bz2,
    const float* __restrict__ bz3) {
  extern __shared__ char smem[];
  int* prog = (int*)(ws + O_PROG);
  if (blockIdx.x < 8) {
    asm volatile("s_setprio 3");
    fps_body<NPT0, M1>(pos, ws + O_POS1, prog, smem, blockIdx.x);
  } else {
    sa_body<NPT0, 0, 32, 32, 64, M1>(
        pos, nullptr, ws + O_POS1, ws + O_X1,
        ws + O_WT1S1, bz1, ws + O_WT2S1, bz2, ws + O_WT3S1, bz3,
        0.04f, prog, smem);
  }
}

__global__ __launch_bounds__(512, 2) void stageB_kernel(
    float* __restrict__ ws,
    const float* __restrict__ bz1, const float* __restrict__ bz2,
    const float* __restrict__ bz3) {
  extern __shared__ char smem[];
  int* prog = (int*)(ws + O_PROG) + 8;
  if (blockIdx.x < 8) {
    asm volatile("s_setprio 3");
    fps_body<M1, M2>(ws + O_POS1, ws + O_POS2, prog, smem, blockIdx.x);
  } else {
    sa_body<M1, 64, 64, 64, 128, M2>(
        ws + O_POS1, ws + O_X1, ws + O_POS2, ws + O_X2,
        ws + O_WT1S2, bz1, ws + O_WT2S2, bz2, ws + O_WT3S2, bz3,
        0.16f, prog, smem);
  }
}

// ---------------------------------------------------------------------------
// SA3 layers 1+2 (131->128->256)
// ---------------------------------------------------------------------------
__global__ __launch_bounds__(256) void sa3_l12_kernel(
    const float* __restrict__ x2, const float* __restrict__ pos2,
    const float* __restrict__ wt1, const float* __restrict__ bz1,
    const float* __restrict__ wt2, const float* __restrict__ bz2,
    float* __restrict__ h2g) {
  __shared__ float H[64 * 132];
  const int tid = threadIdx.x;
  const int lane = tid & 63, w = tid >> 6;
  const int b = blockIdx.x >> 3, tile = blockIdx.x & 7;
  const int pt = tile * 64 + lane;
  const float* xrow = x2 + ((size_t)b * 512 + pt) * 128;
  float* hrow = H + lane * 132;
  const int c0 = w * 32;

  float f[64];
  #pragma unroll
  for (int i = 0; i < 64; i += 4) {
    float4 v = *reinterpret_cast<const float4*>(xrow + i);
    f[i] = v.x; f[i + 1] = v.y; f[i + 2] = v.z; f[i + 3] = v.w;
  }
  for (int c = c0; c < c0 + 32; ++c) {
    const float* wv = wt1 + c * 131;
    float acc = bz1[c];
    #pragma unroll
    for (int i = 0; i < 64; ++i) acc = fmaf(f[i], wv[i], acc);
    hrow[c] = acc;
  }
  #pragma unroll
  for (int i = 0; i < 64; i += 4) {
    float4 v = *reinterpret_cast<const float4*>(xrow + 64 + i);
    f[i] = v.x; f[i + 1] = v.y; f[i + 2] = v.z; f[i + 3] = v.w;
  }
  float q0, q1, q2;
  {
    const float* pr = pos2 + ((size_t)b * 512 + pt) * 3;
    q0 = pr[0]; q1 = pr[1]; q2 = pr[2];
  }
  for (int c = c0; c < c0 + 32; ++c) {
    const float* wv = wt1 + c * 131 + 64;
    float acc = hrow[c];
    #pragma unroll
    for (int i = 0; i < 64; ++i) acc = fmaf(f[i], wv[i], acc);
    acc = fmaf(q0, wv[64], acc);
    acc = fmaf(q1, wv[65], acc);
    acc = fmaf(q2, wv[66], acc);
    hrow[c] = fmaxf(acc, 0.0f);
  }
  __syncthreads();

  float h[128];
  #pragma unroll
  for (int i = 0; i < 128; i += 4) {
    float4 v = *reinterpret_cast<const float4*>(hrow + i);
    h[i] = v.x; h[i + 1] = v.y; h[i + 2] = v.z; h[i + 3] = v.w;
  }
  float* grow = h2g + ((size_t)b * 512 + pt) * 256;
  const int c1 = w * 64;
  for (int c = c1; c < c1 + 64; ++c) {
    const float* wv = wt2 + c * 128;
    float acc = bz2[c];
    #pragma unroll
    for (int i = 0; i < 128; ++i) acc = fmaf(h[i], wv[i], acc);
    grow[c] = fmaxf(acc, 0.0f);
  }
}

// ---------------------------------------------------------------------------
// SA3 layer 3 (256->512) + per-tile max
// ---------------------------------------------------------------------------
__global__ __launch_bounds__(256) void sa3_l3_kernel(
    const float* __restrict__ h2g, const float* __restrict__ w3,
    const float* __restrict__ bz3, float* __restrict__ fpart) {
  const int tid = threadIdx.x;
  const int blk = blockIdx.x;
  const int b   = blk >> 6;
  const int t16 = (blk >> 1) & 31;
  const int cb  = blk & 1;
  const int c = cb * 256 + tid;
  const float* hbase = h2g + ((size_t)b * 512 + t16 * 16) * 256;

  float acc[16];
  #pragma unroll
  for (int j = 0; j < 16; ++j) acc[j] = 0.0f;

  for (int i0 = 0; i0 < 256; i0 += 8) {
    float wv[8];
    #pragma unroll
    for (int u = 0; u < 8; ++u) wv[u] = w3[(size_t)(i0 + u) * 512 + c];
    #pragma unroll
    for (int j = 0; j < 16; ++j) {
      const float* hr = hbase + (size_t)j * 256 + i0;
      #pragma unroll
      for (int u = 0; u < 8; ++u) acc[j] = fmaf(hr[u], wv[u], acc[j]);
    }
  }
  float mv = acc[0];
  #pragma unroll
  for (int j = 1; j < 16; ++j) mv = fmaxf(mv, acc[j]);
  fpart[((size_t)b * 32 + t16) * 512 + c] = mv + bz3[c];
}

// ---------------------------------------------------------------------------
// final
// ---------------------------------------------------------------------------
__global__ __launch_bounds__(64) void final_kernel(
    const float* __restrict__ fpart,
    const float* __restrict__ wmu, const float* __restrict__ bmu,
    const float* __restrict__ wlv, const float* __restrict__ blv,
    float* __restrict__ outp) {
  __shared__ float feat[512];
  const int tid = threadIdx.x;
  const int b = blockIdx.x;
  for (int cidx = tid; cidx < 512; cidx += 64) {
    float mv = fpart[(size_t)b * 32 * 512 + cidx];
    #pragma unroll
    for (int t = 1; t < 32; ++t)
      mv = fmaxf(mv, fpart[((size_t)b * 32 + t) * 512 + cidx]);
    feat[cidx] = mv;
  }
  __syncthreads();
  if (tid < 32) {
    const int c = tid;
    double amu = 0.0, alv = 0.0;
    for (int i = 0; i < 512; ++i) {
      double fv = (double)feat[i];
      amu += fv * (double)wmu[i * 32 + c];
      alv += fv * (double)wlv[i * 32 + c];
    }
    float mu = (float)amu + bmu[c];
    float lv = (float)alv + blv[c];

    uint32_t n = (uint32_t)(b * 32 + c);
    uint32_t o0, o1;
    threefry_0_42(0u, n, o0, o1);
    uint32_t bits = o0 ^ o1;
    float fl = __uint_as_float((bits >> 9) | 0x3f800000u) - 1.0f;
    const float LO = -0.99999994039535522461f;
    float u = fl * 2.0f + LO;
    u = fmaxf(LO, u);
    float eps = 1.4142135623730951f * erfinv_xla(u);
    float z = mu + eps * expf(0.5f * lv);

    outp[b * 32 + c] = z;
    outp[256 + b * 32 + c] = mu;
    outp[512 + b * 32 + c] = lv;
  }
}

// ---------------------------------------------------------------------------
// launcher
// ---------------------------------------------------------------------------
extern "C" void kernel_launch(void* const* d_in, const int* in_sizes, int n_in,
                              void* d_out, int out_size, void* d_ws, size_t ws_size,
                              hipStream_t stream) {
  (void)in_sizes; (void)n_in; (void)out_size; (void)ws_size;
  const float* pos  = (const float*)d_in[0];
  const float* s1w0 = (const float*)d_in[1];  const float* s1b0 = (const float*)d_in[2];
  const float* s1w1 = (const float*)d_in[3];  const float* s1b1 = (const float*)d_in[4];
  const float* s1w2 = (const float*)d_in[5];  const float* s1b2 = (const float*)d_in[6];
  const float* s2w0 = (const float*)d_in[7];  const float* s2b0 = (const float*)d_in[8];
  const float* s2w1 = (const float*)d_in[9];  const float* s2b1 = (const float*)d_in[10];
  const float* s2w2 = (const float*)d_in[11]; const float* s2b2 = (const float*)d_in[12];
  const float* s3w0 = (const float*)d_in[13]; const float* s3b0 = (const float*)d_in[14];
  const float* s3w1 = (const float*)d_in[15]; const float* s3b1 = (const float*)d_in[16];
  const float* s3w2 = (const float*)d_in[17]; const float* s3b2 = (const float*)d_in[18];
  const float* wmu  = (const float*)d_in[19]; const float* bmu  = (const float*)d_in[20];
  const float* wlv  = (const float*)d_in[21]; const float* blv  = (const float*)d_in[22];
  float* ws = (float*)d_ws;
  float* out = (float*)d_out;

  prep_transpose<<<271, 256, 0, stream>>>(s1w0, s1w1, s1w2, s2w0, s2w1, s2w2,
                                          s3w0, s3w1, ws);

  // stage A: 8 producers + 248 persistent consumers = 256 blocks (1/CU)
  stageA_kernel<<<8 + NCONS, 512, 65536, stream>>>(pos, ws, s1b0, s1b1, s1b2);

  // stage B: same layout
  stageB_kernel<<<8 + NCONS, 512, 65536, stream>>>(ws, s2b0, s2b1, s2b2);

  sa3_l12_kernel<<<BATCH * 8, 256, 0, stream>>>(
      ws + O_X2, ws + O_POS2, ws + O_WT1S3, s3b0, ws + O_WT2S3, s3b1,
      ws + O_H2G);

  sa3_l3_kernel<<<BATCH * 64, 256, 0, stream>>>(ws + O_H2G, s3w2, s3b2,
                                                ws + O_FP);

  final_kernel<<<BATCH, 64, 0, stream>>>(ws + O_FP, wmu, bmu, wlv, blv, out);
}